// Round 6
// baseline (79509.497 us; speedup 1.0000x reference)
//
#include <hip/hip_runtime.h>
#include <hip/hip_bf16.h>

// Problem constants
#define T_LEN 2048
#define E_DIM 300
#define H_DIM 512
#define G_DIM 2048   // 4*H
#define NBLK  32     // blocks per (direction,sentence) chain in recurrent kernel
#define UPB   16     // hidden units per block (H/NBLK)
#define TAG_OFF 0x40000000u

// Workspace layout (bytes).
// hbM : MALL exchange buffer  [2 dir][2 parity][2 sent][512] u64 = 16 KB (agent scope, always correct)
// hbL2: XCD-L2 exchange buffer, same layout = 16 KB (fast path when chain is XCD-local)
#define WS_H    0
#define WS_HL2  16384
#define WS_X    32768      // x: [2 sent][2048][300] f32 = 4,915,200 B
#define WS_GX   5242880    // gx: [d*2+s][2048 t][32 bb][4 q][16 ul] bf16 = 33,554,432 B

typedef float v2f __attribute__((ext_vector_type(2)));

__device__ __forceinline__ float sigmoid_fast(float x) {
    return 1.f / (1.f + __expf(-x));
}
__device__ __forceinline__ float tanh_fast(float x) {
    x = fminf(fmaxf(x, -15.f), 15.f);
    float e = __expf(-2.f * x);
    return (1.f - e) / (1.f + e);
}

// dual publish: sc0 store -> write-through to this XCD's L2 (fast, local);
// sc0 sc1 store -> MALL/device coherence point (always correct).
__device__ __forceinline__ void publish2(unsigned long long aL2, unsigned long long aM,
                                         unsigned long long pkt) {
    asm volatile("global_store_dwordx2 %0, %2, off sc0\n\t"
                 "global_store_dwordx2 %1, %2, off sc0 sc1"
                 :: "v"(aL2), "v"(aM), "v"(pkt) : "memory");
}

// ---------------- k1: embedding gather ----------------
__global__ void k_gather(const int* __restrict__ sentA, const int* __restrict__ sentB,
                         const float* __restrict__ emb, float* __restrict__ x) {
    const int s = blockIdx.y;
    const int* sent = s ? sentB : sentA;
    const int t0 = blockIdx.x * 16;
    for (int idx = threadIdx.x; idx < 16 * 300; idx += 256) {
        int r = idx / 300, e = idx - r * 300;
        int t = t0 + r;
        int row = sent[t];
        x[((size_t)(s * 2048 + t)) * 300 + e] = emb[(size_t)row * 300 + e];
    }
}

// ---------------- k2: gx = x @ w_ih^T + (b_ih + b_hh), bf16, block-sliced layout ----------------
__global__ __launch_bounds__(256) void k_gemm(const float* __restrict__ x,
                                              const float* __restrict__ w_ih,
                                              const float* __restrict__ b_ih,
                                              const float* __restrict__ b_hh,
                                              __hip_bfloat16* __restrict__ gx) {
    __shared__ float xs[32 * 108];
    __shared__ float ws_[64 * 108];
    const int gi = blockIdx.x, ti = blockIdx.y, z = blockIdx.z;
    const int d = z >> 1, s = z & 1;
    const int t0 = ti * 32, g0 = gi * 64;
    const int tg = threadIdx.x & 15, tt = threadIdx.x >> 4;
    const float* wbase = w_ih + (size_t)d * G_DIM * E_DIM;

    float acc[2][4];
#pragma unroll
    for (int j = 0; j < 2; ++j)
#pragma unroll
        for (int i = 0; i < 4; ++i) acc[j][i] = 0.f;

    for (int e0 = 0; e0 < 300; e0 += 100) {
        for (int idx = threadIdx.x; idx < 32 * 25; idx += 256) {
            int r = idx / 25, c = idx - r * 25;
            float4 v = *(const float4*)(x + ((size_t)(s * 2048 + t0 + r)) * 300 + e0 + c * 4);
            *(float4*)&xs[r * 108 + c * 4] = v;
        }
        for (int idx = threadIdx.x; idx < 64 * 25; idx += 256) {
            int r = idx / 25, c = idx - r * 25;
            float4 v = *(const float4*)(wbase + (size_t)(g0 + r) * 300 + e0 + c * 4);
            *(float4*)&ws_[r * 108 + c * 4] = v;
        }
        __syncthreads();

        for (int c = 0; c < 25; ++c) {
            float4 xv[2], wv[4];
#pragma unroll
            for (int j = 0; j < 2; ++j) xv[j] = *(const float4*)&xs[(tt + 16 * j) * 108 + c * 4];
#pragma unroll
            for (int i = 0; i < 4; ++i) wv[i] = *(const float4*)&ws_[(tg + 16 * i) * 108 + c * 4];
#pragma unroll
            for (int j = 0; j < 2; ++j)
#pragma unroll
                for (int i = 0; i < 4; ++i)
                    acc[j][i] += xv[j].x * wv[i].x + xv[j].y * wv[i].y +
                                 xv[j].z * wv[i].z + xv[j].w * wv[i].w;
        }
        __syncthreads();
    }

#pragma unroll
    for (int i = 0; i < 4; ++i) {
        int g = g0 + tg + 16 * i;
        float bias = b_ih[d * G_DIM + g] + b_hh[d * G_DIM + g];
        int pos = ((g >> 4) & 31) * 64 + (g >> 9) * 16 + (g & 15);
#pragma unroll
        for (int j = 0; j < 2; ++j) {
            int t = t0 + tt + 16 * j;
            int tout = d ? (T_LEN - 1 - t) : t;
            float v = acc[j][i] + bias;
            gx[(((size_t)(d * 2 + s) * T_LEN + tout) << 11) + pos] = __float2bfloat16(v);
        }
    }
}

// ---------------- k3: recurrent LSTM ----------------
// Grid 256; chain cs = bid&7 (only cs<4 live), bb = bid>>3. Under the
// empirical XCD = bid%8 round-robin mapping, all 32 blocks of a chain land
// on ONE XCD -> the sc0 (L2) exchange path is coherent for them at L2
// latency. Correctness does NOT depend on the mapping: every h packet is
// published to BOTH hbL2 (sc0) and hbM (sc0 sc1 = MALL, R1's proven path),
// and the poll accepts whichever copy's tag matches (per entry).
// Poll: counted-vmcnt ping-pong in inline asm (sets of 4 loads; vmcnt(4)
// waits are newest-relative, so leftover in-flight loads can't skew them).
// Barriers B1/B2 are raw lgkmcnt(0)+s_barrier so in-flight poll loads are
// NOT drained each step (__syncthreads would emit vmcnt(0)).
// Compute phase is R1's proven structure verbatim.
__global__ __launch_bounds__(256, 1) void k_rnn(const float* __restrict__ w_hh,
                                                const __hip_bfloat16* __restrict__ gx,
                                                unsigned long long* __restrict__ hbM,
                                                unsigned long long* __restrict__ hbL2) {
    const int bid = blockIdx.x;
    const int cs  = bid & 7;            // chain (XCD) id
    if (cs >= 4) return;                // 128 live blocks on XCDs 0..3
    const int bb  = bid >> 3;           // 0..31 slice within chain
    const int d   = cs >> 1, s = cs & 1;

    const int tid  = threadIdx.x;
    const int lane = tid & 63;
    const int w    = tid >> 6;          // wave index == gate for matvec
    const int sub  = tid & 3;
    const int q_g  = (tid >> 2) & 3;
    const int ul_g = tid >> 4;

    // persistent weights, row-paired: wreg2[r2][kb] = { W[w*512+bb*16+2r2][k], W[+1][k] }
    v2f wreg2[8][8];
#pragma unroll
    for (int r2 = 0; r2 < 8; ++r2)
#pragma unroll
        for (int kb = 0; kb < 8; ++kb) {
            const float* wp = w_hh + ((size_t)d * G_DIM + w * 512 + bb * 16 + 2 * r2) * H_DIM
                            + kb * 64 + lane;
            v2f t2; t2.x = wp[0]; t2.y = wp[H_DIM];
            wreg2[r2][kb] = t2;
        }

    __shared__ float hlds[H_DIM];       // staged h for this chain (2 KB)
    __shared__ float pacc[64 * 68];     // 64 rows (ul*4+q) x 64 lanes (+4 pad) ~17 KB

    float c_state = 0.f;

    // h_0 = 0, tag TAG_OFF, parity 0 (both buffers)
    if (tid < 16) {
        size_t off = ((size_t)(d * 2 + 0) * 2 + s) * 512 + bb * UPB + tid;
        publish2((unsigned long long)(uintptr_t)(hbL2 + off),
                 (unsigned long long)(uintptr_t)(hbM + off),
                 (unsigned long long)TAG_OFF << 32);
    }
    // zero the per-wave vmcnt baseline (init store counts differ per wave)
    asm volatile("s_waitcnt vmcnt(0)" ::: "memory");
    __builtin_amdgcn_sched_barrier(0);

    // poll indices: wave w owns k-quarter [w*128, w*128+128)
    const int i0 = w * 128 + lane;
    const int i1 = i0 + 64;

    for (int t = 0; t < T_LEN; ++t) {
        const int p  = t & 1;
        const int pn = p ^ 1;
        const unsigned int tag = TAG_OFF + (unsigned int)t;
        const size_t pb = ((size_t)(d * 2 + p) * 2 + s) * 512;

        unsigned long long aL0 = (unsigned long long)(uintptr_t)(hbL2 + pb + i0);
        unsigned long long aL1 = (unsigned long long)(uintptr_t)(hbL2 + pb + i1);
        unsigned long long aM0 = (unsigned long long)(uintptr_t)(hbM + pb + i0);
        unsigned long long aM1 = (unsigned long long)(uintptr_t)(hbM + pb + i1);
        unsigned long long agx = (unsigned long long)(uintptr_t)
            (gx + (((size_t)cs * T_LEN + t) << 11) + bb * 64 + q_g * 16 + ul_g);

        unsigned long long la0, la1, ma0, ma1, lb0, lb1, mb0, mb1;
        unsigned int gxbits;

        // set A (+ gx prefetch): 5 loads
        asm volatile("global_load_ushort %0, %5, off\n\t"
                     "global_load_dwordx2 %1, %6, off sc0\n\t"
                     "global_load_dwordx2 %2, %7, off sc0\n\t"
                     "global_load_dwordx2 %3, %8, off sc0 sc1\n\t"
                     "global_load_dwordx2 %4, %9, off sc0 sc1"
                     : "=&v"(gxbits), "=&v"(la0), "=&v"(la1), "=&v"(ma0), "=&v"(ma1)
                     : "v"(agx), "v"(aL0), "v"(aL1), "v"(aM0), "v"(aM1));
        // set B: 4 loads
        asm volatile("global_load_dwordx2 %0, %4, off sc0\n\t"
                     "global_load_dwordx2 %1, %5, off sc0\n\t"
                     "global_load_dwordx2 %2, %6, off sc0 sc1\n\t"
                     "global_load_dwordx2 %3, %7, off sc0 sc1"
                     : "=&v"(lb0), "=&v"(lb1), "=&v"(mb0), "=&v"(mb1)
                     : "v"(aL0), "v"(aL1), "v"(aM0), "v"(aM1));

        bool useB = false;
        int guard = 0;
        for (;;) {
            // newest 4 = just-issued set; everything older (incl. set A,
            // publish stores, leftovers) is retired by this wait.
            asm volatile("s_waitcnt vmcnt(4)"
                         : "+v"(la0), "+v"(la1), "+v"(ma0), "+v"(ma1));
            __builtin_amdgcn_sched_barrier(0);
            bool ok = (((unsigned int)(la0 >> 32) == tag) | ((unsigned int)(ma0 >> 32) == tag))
                    & (((unsigned int)(la1 >> 32) == tag) | ((unsigned int)(ma1 >> 32) == tag));
            if (__all(ok)) { useB = false; break; }
            if (++guard > (1 << 20)) { useB = false; break; }
            asm volatile("global_load_dwordx2 %0, %4, off sc0\n\t"
                         "global_load_dwordx2 %1, %5, off sc0\n\t"
                         "global_load_dwordx2 %2, %6, off sc0 sc1\n\t"
                         "global_load_dwordx2 %3, %7, off sc0 sc1"
                         : "=&v"(la0), "=&v"(la1), "=&v"(ma0), "=&v"(ma1)
                         : "v"(aL0), "v"(aL1), "v"(aM0), "v"(aM1));
            asm volatile("s_waitcnt vmcnt(4)"
                         : "+v"(lb0), "+v"(lb1), "+v"(mb0), "+v"(mb1));
            __builtin_amdgcn_sched_barrier(0);
            ok = (((unsigned int)(lb0 >> 32) == tag) | ((unsigned int)(mb0 >> 32) == tag))
               & (((unsigned int)(lb1 >> 32) == tag) | ((unsigned int)(mb1 >> 32) == tag));
            if (__all(ok)) { useB = true; break; }
            if (++guard > (1 << 20)) { useB = true; break; }
            asm volatile("global_load_dwordx2 %0, %4, off sc0\n\t"
                         "global_load_dwordx2 %1, %5, off sc0\n\t"
                         "global_load_dwordx2 %2, %6, off sc0 sc1\n\t"
                         "global_load_dwordx2 %3, %7, off sc0 sc1"
                         : "=&v"(lb0), "=&v"(lb1), "=&v"(mb0), "=&v"(mb1)
                         : "v"(aL0), "v"(aL1), "v"(aM0), "v"(aM1));
        }

        // per-entry select: prefer whichever copy carries the tag
        unsigned long long sl0 = useB ? lb0 : la0;
        unsigned long long sm0 = useB ? mb0 : ma0;
        unsigned long long sl1 = useB ? lb1 : la1;
        unsigned long long sm1 = useB ? mb1 : ma1;
        unsigned int v0 = ((unsigned int)(sl0 >> 32) == tag) ? (unsigned int)sl0 : (unsigned int)sm0;
        unsigned int v1 = ((unsigned int)(sl1 >> 32) == tag) ? (unsigned int)sl1 : (unsigned int)sm1;

        // stage this wave's quarter into LDS
        hlds[i0] = __uint_as_float(v0);
        hlds[i1] = __uint_as_float(v1);
        // B1: raw barrier (lgkm only -- do NOT drain in-flight poll loads)
        asm volatile("s_waitcnt lgkmcnt(0)\n\ts_barrier" ::: "memory");
        __builtin_amdgcn_sched_barrier(0);

        float gxv = __uint_as_float(gxbits << 16);   // bf16 -> f32

        // load full h fragment for this lane
        float hv[8];
#pragma unroll
        for (int kb = 0; kb < 8; ++kb)
            hv[kb] = hlds[kb * 64 + lane];

        // matvec partials: 8 row-pairs per lane, packed fp32 FMA (64 v2f)
        v2f acc2[8];
#pragma unroll
        for (int r2 = 0; r2 < 8; ++r2) acc2[r2] = (v2f)(0.f);
#pragma unroll
        for (int kb = 0; kb < 8; ++kb) {
            float h0 = hv[kb];
            v2f h2; h2.x = h0; h2.y = h0;
#pragma unroll
            for (int r2 = 0; r2 < 8; ++r2)
                acc2[r2] += wreg2[r2][kb] * h2;
        }

        // publish partials: physical row index = ul*4 + q (q = this wave w)
#pragma unroll
        for (int r2 = 0; r2 < 8; ++r2) {
            pacc[((2 * r2 + 0) * 4 + w) * 68 + lane] = acc2[r2].x;
            pacc[((2 * r2 + 1) * 4 + w) * 68 + lane] = acc2[r2].y;
        }
        // B2: raw barrier
        asm volatile("s_waitcnt lgkmcnt(0)\n\ts_barrier" ::: "memory");
        __builtin_amdgcn_sched_barrier(0);

        // reduce row r_phys = ul*4 + q = tid>>2: 4 threads x 16 values
        const float4* pr = (const float4*)&pacc[(tid >> 2) * 68 + sub * 16];
        float4 sv = pr[0];
#pragma unroll
        for (int j2 = 1; j2 < 4; ++j2) {
            float4 q4 = pr[j2];
            sv.x += q4.x; sv.y += q4.y; sv.z += q4.z; sv.w += q4.w;
        }
        float v = (sv.x + sv.y) + (sv.z + sv.w);
        v += __shfl_xor(v, 1, 64);
        v += __shfl_xor(v, 2, 64);
        v += gxv;
        float act = (q_g == 2) ? tanh_fast(v) : sigmoid_fast(v);

        // gather i/f/g/o within the 16-lane group (lanes g0l+4q)
        const int g0l = lane & ~15;
        float si = __shfl(act, g0l + 0,  64);
        float sf = __shfl(act, g0l + 4,  64);
        float tg = __shfl(act, g0l + 8,  64);
        float so = __shfl(act, g0l + 12, 64);
        if ((lane & 15) == 0) {
            c_state = sf * c_state + si * tg;
            float h_new = so * tanh_fast(c_state);
            unsigned long long pkt = ((unsigned long long)(tag + 1u) << 32)
                                   | (unsigned long long)__float_as_uint(h_new);
            size_t po = ((size_t)(d * 2 + pn) * 2 + s) * 512 + bb * UPB + ul_g;
            publish2((unsigned long long)(uintptr_t)(hbL2 + po),
                     (unsigned long long)(uintptr_t)(hbM + po), pkt);
        }
        // pacc/hlds WAR across steps protected by B1/B2 (R1 argument).
        // vmcnt bookkeeping: waits are newest-relative, so leftover poll
        // loads and publish stores retire under the next step's vmcnt(4).
    }
}

// ---------------- k4: head ----------------
__global__ __launch_bounds__(512) void k_head(const unsigned long long* __restrict__ hb,
                                              const float* __restrict__ bi_w,
                                              const float* __restrict__ bi_b,
                                              const float* __restrict__ blA,
                                              const float* __restrict__ blB,
                                              const float* __restrict__ bl_b,
                                              const float* __restrict__ out_w,
                                              const float* __restrict__ out_b,
                                              float* __restrict__ out) {
    __shared__ float enc[2][512];
    __shared__ float red[8];
    const int tid = threadIdx.x;
    const float bw0 = bi_w[0], bw1 = bi_w[1], bib = bi_b[0];
    {
        int u = tid;
        // final h (t=2048) lives in parity 0 of hbM
        float hfA = __uint_as_float((unsigned int)hb[((0 * 2 + 0) * 2 + 0) * 512 + u]);
        float hbA = __uint_as_float((unsigned int)hb[((1 * 2 + 0) * 2 + 0) * 512 + u]);
        float hfB = __uint_as_float((unsigned int)hb[((0 * 2 + 0) * 2 + 1) * 512 + u]);
        float hbB = __uint_as_float((unsigned int)hb[((1 * 2 + 0) * 2 + 1) * 512 + u]);
        enc[0][u] = bw0 * hfA + bw1 * hbA + bib;
        enc[1][u] = bw0 * hfB + bw1 * hbB + bib;
    }
    __syncthreads();
    const int j = tid;
    float acc = bl_b[j];
#pragma unroll 4
    for (int u = 0; u < 512; ++u)
        acc += enc[0][u] * blA[u * 512 + j] + enc[1][u] * blB[u * 512 + j];
    float contrib = tanh_fast(acc) * out_w[j];
#pragma unroll
    for (int m = 1; m < 64; m <<= 1) contrib += __shfl_xor(contrib, m, 64);
    if ((tid & 63) == 0) red[tid >> 6] = contrib;
    __syncthreads();
    if (tid == 0) {
        float s = 0.f;
#pragma unroll
        for (int i = 0; i < 8; ++i) s += red[i];
        s += out_b[0];
        out[0] = sigmoid_fast(s);
    }
}

extern "C" void kernel_launch(void* const* d_in, const int* in_sizes, int n_in,
                              void* d_out, int out_size, void* d_ws, size_t ws_size,
                              hipStream_t stream) {
    const int*   sentA = (const int*)d_in[0];
    const int*   sentB = (const int*)d_in[1];
    // d_in[2] = hidden (unused by forward)
    const float* emb   = (const float*)d_in[3];
    const float* w_ih  = (const float*)d_in[4];
    const float* w_hh  = (const float*)d_in[5];
    const float* b_ih  = (const float*)d_in[6];
    const float* b_hh  = (const float*)d_in[7];
    const float* bi_w  = (const float*)d_in[8];
    const float* bi_b  = (const float*)d_in[9];
    const float* blA   = (const float*)d_in[10];
    const float* blB   = (const float*)d_in[11];
    const float* bl_b  = (const float*)d_in[12];
    const float* out_w = (const float*)d_in[13];
    const float* out_b = (const float*)d_in[14];
    float* out = (float*)d_out;

    char* ws = (char*)d_ws;
    unsigned long long* hbM  = (unsigned long long*)(ws + WS_H);
    unsigned long long* hbL2 = (unsigned long long*)(ws + WS_HL2);
    float*              x    = (float*)(ws + WS_X);
    __hip_bfloat16*     gx   = (__hip_bfloat16*)(ws + WS_GX);

    k_gather<<<dim3(128, 2), 256, 0, stream>>>(sentA, sentB, emb, x);
    k_gemm<<<dim3(32, 64, 4), 256, 0, stream>>>(x, w_ih, b_ih, b_hh, gx);
    k_rnn<<<dim3(256), 256, 0, stream>>>(w_hh, gx, hbM, hbL2);
    k_head<<<dim3(1), 512, 0, stream>>>(hbM, bi_w, bi_b, blA, blB, bl_b, out_w, out_b, out);
}

// Round 7
// 4415.233 us; speedup vs baseline: 18.0080x; 18.0080x over previous
//
#include <hip/hip_runtime.h>
#include <hip/hip_bf16.h>

// Problem constants
#define T_LEN 2048
#define E_DIM 300
#define H_DIM 512
#define G_DIM 2048   // 4*H
#define NBLK  32     // blocks per (direction,sentence) chain in recurrent kernel
#define UPB   16     // hidden units per block (H/NBLK)
#define TAG_OFF 0x40000000u

// Workspace layout (bytes).
// hb: (value,tag) pairs [2 dir][2 parity][2 sent][512] u64 = 16 KB
#define WS_H   0
#define WS_X   16384       // x: [2 sent][2048][300] f32 = 4,915,200 B
#define WS_GX  5242880     // gx: [d*2+s][2048 t][32 bb][4 q][16 ul] bf16 = 33,554,432 B

typedef float v2f __attribute__((ext_vector_type(2)));

__device__ __forceinline__ float sigmoid_fast(float x) {
    return 1.f / (1.f + __expf(-x));
}
__device__ __forceinline__ float tanh_fast(float x) {
    x = fminf(fmaxf(x, -15.f), 15.f);
    float e = __expf(-2.f * x);
    return (1.f - e) / (1.f + e);
}

// ---------------- k1: embedding gather ----------------
__global__ void k_gather(const int* __restrict__ sentA, const int* __restrict__ sentB,
                         const float* __restrict__ emb, float* __restrict__ x) {
    const int s = blockIdx.y;
    const int* sent = s ? sentB : sentA;
    const int t0 = blockIdx.x * 16;
    for (int idx = threadIdx.x; idx < 16 * 300; idx += 256) {
        int r = idx / 300, e = idx - r * 300;
        int t = t0 + r;
        int row = sent[t];
        x[((size_t)(s * 2048 + t)) * 300 + e] = emb[(size_t)row * 300 + e];
    }
}

// ---------------- k2: gx = x @ w_ih^T + (b_ih + b_hh), bf16, block-sliced layout ----------------
// grid (32 gi, 64 ti, 4 = d*2+s), block 256. Both tiles staged in LDS
// (coalesced global loads); K chunked 3x100.
__global__ __launch_bounds__(256) void k_gemm(const float* __restrict__ x,
                                              const float* __restrict__ w_ih,
                                              const float* __restrict__ b_ih,
                                              const float* __restrict__ b_hh,
                                              __hip_bfloat16* __restrict__ gx) {
    // stride 108 floats (432B, 16B-aligned rows; 108 mod 32 = 12 -> <=2-way banks)
    __shared__ float xs[32 * 108];
    __shared__ float ws_[64 * 108];
    const int gi = blockIdx.x, ti = blockIdx.y, z = blockIdx.z;
    const int d = z >> 1, s = z & 1;
    const int t0 = ti * 32, g0 = gi * 64;
    const int tg = threadIdx.x & 15, tt = threadIdx.x >> 4;
    const float* wbase = w_ih + (size_t)d * G_DIM * E_DIM;

    float acc[2][4];
#pragma unroll
    for (int j = 0; j < 2; ++j)
#pragma unroll
        for (int i = 0; i < 4; ++i) acc[j][i] = 0.f;

    for (int e0 = 0; e0 < 300; e0 += 100) {
        // stage x tile: 32 rows x 25 float4
        for (int idx = threadIdx.x; idx < 32 * 25; idx += 256) {
            int r = idx / 25, c = idx - r * 25;
            float4 v = *(const float4*)(x + ((size_t)(s * 2048 + t0 + r)) * 300 + e0 + c * 4);
            *(float4*)&xs[r * 108 + c * 4] = v;
        }
        // stage w tile: 64 rows x 25 float4
        for (int idx = threadIdx.x; idx < 64 * 25; idx += 256) {
            int r = idx / 25, c = idx - r * 25;
            float4 v = *(const float4*)(wbase + (size_t)(g0 + r) * 300 + e0 + c * 4);
            *(float4*)&ws_[r * 108 + c * 4] = v;
        }
        __syncthreads();

        for (int c = 0; c < 25; ++c) {
            float4 xv[2], wv[4];
#pragma unroll
            for (int j = 0; j < 2; ++j) xv[j] = *(const float4*)&xs[(tt + 16 * j) * 108 + c * 4];
#pragma unroll
            for (int i = 0; i < 4; ++i) wv[i] = *(const float4*)&ws_[(tg + 16 * i) * 108 + c * 4];
#pragma unroll
            for (int j = 0; j < 2; ++j)
#pragma unroll
                for (int i = 0; i < 4; ++i)
                    acc[j][i] += xv[j].x * wv[i].x + xv[j].y * wv[i].y +
                                 xv[j].z * wv[i].z + xv[j].w * wv[i].w;
        }
        __syncthreads();
    }

#pragma unroll
    for (int i = 0; i < 4; ++i) {
        int g = g0 + tg + 16 * i;
        float bias = b_ih[d * G_DIM + g] + b_hh[d * G_DIM + g];
        // block-sliced position: [bb][q][ul]
        int pos = ((g >> 4) & 31) * 64 + (g >> 9) * 16 + (g & 15);
#pragma unroll
        for (int j = 0; j < 2; ++j) {
            int t = t0 + tt + 16 * j;
            int tout = d ? (T_LEN - 1 - t) : t;   // backward run: time-reversed rows
            float v = acc[j][i] + bias;
            gx[(((size_t)(d * 2 + s) * T_LEN + tout) << 11) + pos] = __float2bfloat16(v);
        }
    }
}

// ---------------- k3: recurrent LSTM, 128 blocks = (2 dir x 2 sent x 32) ----------------
// One block per chain-slice: owns 16 hidden units x 4 gates of ONE (dir,sent)
// chain. h exchanged as (u32 step tag | fp32 value) u64 agent-scope atomics.
// Wave w polls ONLY its k-quarter of its own sentence (2 loads/lane,
// ping-pong pipelined), stages to LDS; B1; all waves read full h from LDS.
// Reduce identity tid = ul*16 + q*4 + sub keeps i/f/g/o in one 16-lane
// group -> shfl gather, no third barrier.
// [R2-R6 post-mortems: block-merge, bf16-packing, 32x replication,
//  barrier-free wave-autonomy, and sc0 L2-handoff ALL regressed. This
//  geometry (64 lines/chain, quarter-split poll, 2-deep ping-pong,
//  16 contiguous publish stores) is the measured optimum; the round is
//  bounded by one agent-scope MALL round-trip (~1.5us), invariant to
//  exchange volume/fan-out/packing/barrier count.]
__global__ __launch_bounds__(256, 1) void k_rnn(const float* __restrict__ w_hh,
                                                const __hip_bfloat16* __restrict__ gx,
                                                unsigned long long* __restrict__ hb) {
    const int tid  = threadIdx.x;
    const int lane = tid & 63;
    const int w    = tid >> 6;          // wave index == gate row-block for matvec
    // reduce/gate-phase identity: tid = ul*16 + q*4 + sub
    const int sub  = tid & 3;
    const int q_g  = (tid >> 2) & 3;
    const int ul_g = tid >> 4;
    const int bid = blockIdx.x;         // (d*2+s)*32 + bb
    const int d  = bid >> 6;
    const int s  = (bid >> 5) & 1;
    const int bb = bid & 31;

    // persistent weights, row-paired: wreg2[r2][kb] = { W[w*512+bb*16+2r2][k], W[+1][k] }
    v2f wreg2[8][8];
#pragma unroll
    for (int r2 = 0; r2 < 8; ++r2)
#pragma unroll
        for (int kb = 0; kb < 8; ++kb) {
            const float* wp = w_hh + ((size_t)d * G_DIM + w * 512 + bb * 16 + 2 * r2) * H_DIM
                            + kb * 64 + lane;
            v2f t2; t2.x = wp[0]; t2.y = wp[H_DIM];
            wreg2[r2][kb] = t2;
        }

    __shared__ float hlds[H_DIM];       // staged h for this chain (2 KB)
    __shared__ float pacc[64 * 68];     // 64 rows (ul*4+q) x 64 lanes (+4 pad) ~17 KB

    float c_state = 0.f;

    // h_0 = 0, tag TAG_OFF, parity 0 (published by the 16 state-carrier threads)
    if ((lane & 15) == 0) {
        __hip_atomic_store(&hb[((size_t)(d * 2 + 0) * 2 + s) * H_DIM + bb * UPB + ul_g],
                           (unsigned long long)TAG_OFF << 32,
                           __ATOMIC_RELAXED, __HIP_MEMORY_SCOPE_AGENT);
    }

    // poll indices: wave w owns k-quarter [w*128, w*128+128) of its sentence
    const int i0 = w * 128 + lane;
    const int i1 = i0 + 64;

    for (int t = 0; t < T_LEN; ++t) {
        const int p  = t & 1;
        const int pn = p ^ 1;

        // prefetch this thread's gate input (overlaps the poll)
        float gxv = (float)gx[(((size_t)(d * 2 + s) * T_LEN + t) << 11)
                              + bb * 64 + q_g * 16 + ul_g];

        unsigned long long* hbp = hb + ((size_t)(d * 2 + p) * 2 + s) * H_DIM;
        const unsigned int tag = TAG_OFF + (unsigned int)t;
        unsigned long long a0, a1, b0, b1;

#define LDH(X) __hip_atomic_load(&hbp[X], __ATOMIC_RELAXED, __HIP_MEMORY_SCOPE_AGENT)
        // ping-pong poll: two independent register sets, ~RT/2 detect granularity
        a0 = LDH(i0); a1 = LDH(i1);
        int guard = 0;
        for (;;) {
            b0 = LDH(i0); b1 = LDH(i1);
            bool okA = ((unsigned int)(a0 >> 32) == tag) & ((unsigned int)(a1 >> 32) == tag);
            if (__all(okA)) break;
            if (++guard > (1 << 20)) break;
            a0 = LDH(i0); a1 = LDH(i1);
            bool okB = ((unsigned int)(b0 >> 32) == tag) & ((unsigned int)(b1 >> 32) == tag);
            if (__all(okB)) { a0 = b0; a1 = b1; break; }
            if (++guard > (1 << 20)) break;
        }
#undef LDH

        // stage this wave's quarter into LDS
        hlds[i0] = __uint_as_float((unsigned int)a0);
        hlds[i1] = __uint_as_float((unsigned int)a1);
        __syncthreads();   // B1: full h visible to all waves

        // load full h fragment for this lane
        float hv[8];
#pragma unroll
        for (int kb = 0; kb < 8; ++kb)
            hv[kb] = hlds[kb * 64 + lane];

        // matvec partials: 8 row-pairs per lane, packed fp32 FMA (64 v2f)
        v2f acc2[8];
#pragma unroll
        for (int r2 = 0; r2 < 8; ++r2) acc2[r2] = (v2f)(0.f);
#pragma unroll
        for (int kb = 0; kb < 8; ++kb) {
            float h0 = hv[kb];
            v2f h2; h2.x = h0; h2.y = h0;
#pragma unroll
            for (int r2 = 0; r2 < 8; ++r2)
                acc2[r2] += wreg2[r2][kb] * h2;
        }

        // publish partials: physical row index = ul*4 + q (q = this wave w)
#pragma unroll
        for (int r2 = 0; r2 < 8; ++r2) {
            pacc[((2 * r2 + 0) * 4 + w) * 68 + lane] = acc2[r2].x;
            pacc[((2 * r2 + 1) * 4 + w) * 68 + lane] = acc2[r2].y;
        }
        __syncthreads();   // B2

        // reduce row r_phys = ul*4 + q = tid>>2: 4 threads x 16 values
        const float4* pr = (const float4*)&pacc[(tid >> 2) * 68 + sub * 16];
        float4 sv = pr[0];
#pragma unroll
        for (int j2 = 1; j2 < 4; ++j2) {
            float4 q4 = pr[j2];
            sv.x += q4.x; sv.y += q4.y; sv.z += q4.z; sv.w += q4.w;
        }
        float v = (sv.x + sv.y) + (sv.z + sv.w);
        v += __shfl_xor(v, 1, 64);
        v += __shfl_xor(v, 2, 64);
        v += gxv;
        float act = (q_g == 2) ? tanh_fast(v) : sigmoid_fast(v);

        // gather i/f/g/o within the 16-lane group (lanes g0l+4q), update, publish
        const int g0l = lane & ~15;
        float si = __shfl(act, g0l + 0,  64);
        float sf = __shfl(act, g0l + 4,  64);
        float tg = __shfl(act, g0l + 8,  64);
        float so = __shfl(act, g0l + 12, 64);
        if ((lane & 15) == 0) {
            c_state = sf * c_state + si * tg;
            float h_new = so * tanh_fast(c_state);
            unsigned long long pkt = ((unsigned long long)(TAG_OFF + (unsigned int)(t + 1)) << 32)
                                   | (unsigned long long)__float_as_uint(h_new);
            __hip_atomic_store(&hb[((size_t)(d * 2 + pn) * 2 + s) * H_DIM + bb * UPB + ul_g],
                               pkt, __ATOMIC_RELAXED, __HIP_MEMORY_SCOPE_AGENT);
        }
        // pacc/hlds WAR across steps protected by B1/B2:
        // any wave passing poll(t+1) implies ALL this block's waves published
        // step t (each wave publishes 4 of the 16 units), which in program
        // order follows their hlds/pacc reads for step t.
    }
}

// ---------------- k4: head ----------------
__global__ __launch_bounds__(512) void k_head(const unsigned long long* __restrict__ hb,
                                              const float* __restrict__ bi_w,
                                              const float* __restrict__ bi_b,
                                              const float* __restrict__ blA,
                                              const float* __restrict__ blB,
                                              const float* __restrict__ bl_b,
                                              const float* __restrict__ out_w,
                                              const float* __restrict__ out_b,
                                              float* __restrict__ out) {
    __shared__ float enc[2][512];
    __shared__ float red[8];
    const int tid = threadIdx.x;
    const float bw0 = bi_w[0], bw1 = bi_w[1], bib = bi_b[0];
    {
        int u = tid;
        // final h (t=2048) lives in parity 0
        float hfA = __uint_as_float((unsigned int)hb[((0 * 2 + 0) * 2 + 0) * 512 + u]);
        float hbA = __uint_as_float((unsigned int)hb[((1 * 2 + 0) * 2 + 0) * 512 + u]);
        float hfB = __uint_as_float((unsigned int)hb[((0 * 2 + 0) * 2 + 1) * 512 + u]);
        float hbB = __uint_as_float((unsigned int)hb[((1 * 2 + 0) * 2 + 1) * 512 + u]);
        enc[0][u] = bw0 * hfA + bw1 * hbA + bib;
        enc[1][u] = bw0 * hfB + bw1 * hbB + bib;
    }
    __syncthreads();
    const int j = tid;
    float acc = bl_b[j];
#pragma unroll 4
    for (int u = 0; u < 512; ++u)
        acc += enc[0][u] * blA[u * 512 + j] + enc[1][u] * blB[u * 512 + j];
    float contrib = tanh_fast(acc) * out_w[j];
#pragma unroll
    for (int m = 1; m < 64; m <<= 1) contrib += __shfl_xor(contrib, m, 64);
    if ((tid & 63) == 0) red[tid >> 6] = contrib;
    __syncthreads();
    if (tid == 0) {
        float s = 0.f;
#pragma unroll
        for (int i = 0; i < 8; ++i) s += red[i];
        s += out_b[0];
        out[0] = sigmoid_fast(s);
    }
}

extern "C" void kernel_launch(void* const* d_in, const int* in_sizes, int n_in,
                              void* d_out, int out_size, void* d_ws, size_t ws_size,
                              hipStream_t stream) {
    const int*   sentA = (const int*)d_in[0];
    const int*   sentB = (const int*)d_in[1];
    // d_in[2] = hidden (unused by forward)
    const float* emb   = (const float*)d_in[3];
    const float* w_ih  = (const float*)d_in[4];
    const float* w_hh  = (const float*)d_in[5];
    const float* b_ih  = (const float*)d_in[6];
    const float* b_hh  = (const float*)d_in[7];
    const float* bi_w  = (const float*)d_in[8];
    const float* bi_b  = (const float*)d_in[9];
    const float* blA   = (const float*)d_in[10];
    const float* blB   = (const float*)d_in[11];
    const float* bl_b  = (const float*)d_in[12];
    const float* out_w = (const float*)d_in[13];
    const float* out_b = (const float*)d_in[14];
    float* out = (float*)d_out;

    char* ws = (char*)d_ws;
    unsigned long long* hbf = (unsigned long long*)(ws + WS_H);
    float*              x   = (float*)(ws + WS_X);
    __hip_bfloat16*     gx  = (__hip_bfloat16*)(ws + WS_GX);

    k_gather<<<dim3(128, 2), 256, 0, stream>>>(sentA, sentB, emb, x);
    k_gemm<<<dim3(32, 64, 4), 256, 0, stream>>>(x, w_ih, b_ih, b_hh, gx);
    k_rnn<<<dim3(128), 256, 0, stream>>>(w_hh, gx, hbf);
    k_head<<<dim3(1), 512, 0, stream>>>(hbf, bi_w, bi_b, blA, blB, bl_b, out_w, out_b, out);
}

// Round 8
// 4246.446 us; speedup vs baseline: 18.7238x; 1.0397x over previous
//
#include <hip/hip_runtime.h>
#include <hip/hip_bf16.h>

// Problem constants
#define T_LEN 2048
#define E_DIM 300
#define H_DIM 512
#define G_DIM 2048   // 4*H
#define NBLK  32     // blocks per (direction,sentence) chain in recurrent kernel
#define UPB   16     // hidden units per block (H/NBLK)
#define TAG_OFF 0x40000000u

// Workspace layout (bytes).
// hb: (value,tag) pairs [2 dir][2 parity][2 sent][512] u64 = 32 KB; the
// d=1 half overlaps the head of x — safe: x fully consumed by k_gemm
// before k_rnn's first store (same stream).
#define WS_H    0
#define WS_X    16384      // x: [2 sent][2048][300] f32 = 4,915,200 B
#define WS_GX   5242880    // gx: [d*2+s][2048 t][32 bb][4 q][16 ul] bf16 = 33,554,432 B
#define WS_OUT  38797312   // head partials: 16 f32

typedef float v2f __attribute__((ext_vector_type(2)));
typedef __attribute__((ext_vector_type(8))) short bf16x8;
typedef __attribute__((ext_vector_type(4))) float f32x4;

__device__ __forceinline__ float sigmoid_fast(float x) {
    return 1.f / (1.f + __expf(-x));
}
__device__ __forceinline__ float tanh_fast(float x) {
    x = fminf(fmaxf(x, -15.f), 15.f);
    float e = __expf(-2.f * x);
    return (1.f - e) / (1.f + e);
}
__device__ __forceinline__ unsigned short bf16b(float f) {
    __hip_bfloat16 h = __float2bfloat16(f);   // RNE
    unsigned short u; __builtin_memcpy(&u, &h, 2); return u;
}

// ---------------- k1: embedding gather ----------------
__global__ void k_gather(const int* __restrict__ sentA, const int* __restrict__ sentB,
                         const float* __restrict__ emb, float* __restrict__ x) {
    const int s = blockIdx.y;
    const int* sent = s ? sentB : sentA;
    const int t0 = blockIdx.x * 16;
    for (int idx = threadIdx.x; idx < 16 * 300; idx += 256) {
        int r = idx / 300, e = idx - r * 300;
        int t = t0 + r;
        int row = sent[t];
        x[((size_t)(s * 2048 + t)) * 300 + e] = emb[(size_t)row * 300 + e];
    }
}

// ---------------- k2: gx = x @ w_ih^T + (b_ih + b_hh), bf16 MFMA ----------------
// grid (32 gi, 64 ti, 4 = d*2+s), block 256 (4 waves). Block tile 32t x 64g,
// K=300 zero-padded to 320, 10 chunks of 32. Inputs fp32 -> bf16 at staging
// (output is stored bf16 anyway; gate nonlinearities tolerate ~2^-9 rel).
// Fragment pattern (guide m89/m92-verified): A = x rows [M][K], B = w rows
// [N][K] (B^T layout); both read as 8-bf16 runs at [lane&15][(lane>>4)*8];
// C/D: col(g)=lane&15, row(t)=(lane>>4)*4+reg.
#define KP 328   // padded LDS row stride in ushort (656B; 2-way banks on frag reads)
__global__ __launch_bounds__(256) void k_gemm(const float* __restrict__ x,
                                              const float* __restrict__ w_ih,
                                              const float* __restrict__ b_ih,
                                              const float* __restrict__ b_hh,
                                              __hip_bfloat16* __restrict__ gx) {
    __shared__ unsigned short xs[32 * KP];
    __shared__ unsigned short ws_[64 * KP];
    const int gi = blockIdx.x, ti = blockIdx.y, z = blockIdx.z;
    const int d = z >> 1, s = z & 1;
    const int t0 = ti * 32, g0 = gi * 64;
    const int tid  = threadIdx.x;
    const int lane = tid & 63, w = tid >> 6;
    const float* wbase = w_ih + (size_t)d * G_DIM * E_DIM;

    // stage x tile: 32 rows x 320 bf16 (zero-pad e in [300,320))
    for (int idx = tid; idx < 32 * 80; idx += 256) {
        int r = idx / 80, c = idx - r * 80;   // c in float4 units
        float4 v = {0.f, 0.f, 0.f, 0.f};
        if (c < 75) v = *(const float4*)(x + ((size_t)(s * 2048 + t0 + r)) * 300 + c * 4);
        ushort4 o; o.x = bf16b(v.x); o.y = bf16b(v.y); o.z = bf16b(v.z); o.w = bf16b(v.w);
        *(ushort4*)&xs[r * KP + c * 4] = o;
    }
    // stage w tile: 64 rows x 320 bf16
    for (int idx = tid; idx < 64 * 80; idx += 256) {
        int r = idx / 80, c = idx - r * 80;
        float4 v = {0.f, 0.f, 0.f, 0.f};
        if (c < 75) v = *(const float4*)(wbase + (size_t)(g0 + r) * 300 + c * 4);
        ushort4 o; o.x = bf16b(v.x); o.y = bf16b(v.y); o.z = bf16b(v.z); o.w = bf16b(v.w);
        *(ushort4*)&ws_[r * KP + c * 4] = o;
    }
    __syncthreads();

    // wave w: m-strip mw = (w&1)*16, n-base nb = (w>>1)*32 (two 16-wide n-tiles)
    const int mw = (w & 1) * 16, nb = (w >> 1) * 32;
    const int fm = lane & 15;           // fragment m/n index
    const int fk = (lane >> 4) * 8;     // k offset within chunk
    f32x4 acc0 = {0.f, 0.f, 0.f, 0.f};
    f32x4 acc1 = {0.f, 0.f, 0.f, 0.f};
#pragma unroll
    for (int e0 = 0; e0 < 320; e0 += 32) {
        bf16x8 av  = *(const bf16x8*)&xs[(mw + fm) * KP + e0 + fk];
        bf16x8 bv0 = *(const bf16x8*)&ws_[(nb + fm) * KP + e0 + fk];
        bf16x8 bv1 = *(const bf16x8*)&ws_[(nb + 16 + fm) * KP + e0 + fk];
        acc0 = __builtin_amdgcn_mfma_f32_16x16x32_bf16(av, bv0, acc0, 0, 0, 0);
        acc1 = __builtin_amdgcn_mfma_f32_16x16x32_bf16(av, bv1, acc1, 0, 0, 0);
    }

    // epilogue: bias + bf16 store into block-sliced layout
    const int trowb = (lane >> 4) * 4;
#pragma unroll
    for (int nt = 0; nt < 2; ++nt) {
        f32x4 a = nt ? acc1 : acc0;
        int g = g0 + nb + nt * 16 + fm;
        float bias = b_ih[d * G_DIM + g] + b_hh[d * G_DIM + g];
        int pos = ((g >> 4) & 31) * 64 + (g >> 9) * 16 + (g & 15);
#pragma unroll
        for (int i = 0; i < 4; ++i) {
            int t = t0 + mw + trowb + i;
            int tout = d ? (T_LEN - 1 - t) : t;   // backward run: time-reversed rows
            gx[(((size_t)z * T_LEN + tout) << 11) + pos] = __float2bfloat16(a[i] + bias);
        }
    }
}

// ---------------- k3: recurrent LSTM, 128 blocks = (2 dir x 2 sent x 32) ----------------
// BYTE-IDENTICAL to the R1/R7-verified kernel (3925us reproduced twice).
// [R2-R6 post-mortems: block-merge, bf16-packing, 32x replication,
//  barrier-free wave-autonomy, and sc0 L2-handoff ALL regressed. This
//  geometry (64 lines/chain, quarter-split poll, 2-deep ping-pong,
//  16 contiguous publish stores) is the measured optimum; the round is
//  bounded by one agent-scope MALL round-trip (~1.5us), invariant to
//  exchange volume/fan-out/packing/barrier count.]
__global__ __launch_bounds__(256, 1) void k_rnn(const float* __restrict__ w_hh,
                                                const __hip_bfloat16* __restrict__ gx,
                                                unsigned long long* __restrict__ hb) {
    const int tid  = threadIdx.x;
    const int lane = tid & 63;
    const int w    = tid >> 6;          // wave index == gate row-block for matvec
    // reduce/gate-phase identity: tid = ul*16 + q*4 + sub
    const int sub  = tid & 3;
    const int q_g  = (tid >> 2) & 3;
    const int ul_g = tid >> 4;
    const int bid = blockIdx.x;         // (d*2+s)*32 + bb
    const int d  = bid >> 6;
    const int s  = (bid >> 5) & 1;
    const int bb = bid & 31;

    // persistent weights, row-paired: wreg2[r2][kb] = { W[w*512+bb*16+2r2][k], W[+1][k] }
    v2f wreg2[8][8];
#pragma unroll
    for (int r2 = 0; r2 < 8; ++r2)
#pragma unroll
        for (int kb = 0; kb < 8; ++kb) {
            const float* wp = w_hh + ((size_t)d * G_DIM + w * 512 + bb * 16 + 2 * r2) * H_DIM
                            + kb * 64 + lane;
            v2f t2; t2.x = wp[0]; t2.y = wp[H_DIM];
            wreg2[r2][kb] = t2;
        }

    __shared__ float hlds[H_DIM];       // staged h for this chain (2 KB)
    __shared__ float pacc[64 * 68];     // 64 rows (ul*4+q) x 64 lanes (+4 pad) ~17 KB

    float c_state = 0.f;

    // h_0 = 0, tag TAG_OFF, parity 0 (published by the 16 state-carrier threads)
    if ((lane & 15) == 0) {
        __hip_atomic_store(&hb[((size_t)(d * 2 + 0) * 2 + s) * H_DIM + bb * UPB + ul_g],
                           (unsigned long long)TAG_OFF << 32,
                           __ATOMIC_RELAXED, __HIP_MEMORY_SCOPE_AGENT);
    }

    // poll indices: wave w owns k-quarter [w*128, w*128+128) of its sentence
    const int i0 = w * 128 + lane;
    const int i1 = i0 + 64;

    for (int t = 0; t < T_LEN; ++t) {
        const int p  = t & 1;
        const int pn = p ^ 1;

        // prefetch this thread's gate input (overlaps the poll)
        float gxv = (float)gx[(((size_t)(d * 2 + s) * T_LEN + t) << 11)
                              + bb * 64 + q_g * 16 + ul_g];

        unsigned long long* hbp = hb + ((size_t)(d * 2 + p) * 2 + s) * H_DIM;
        const unsigned int tag = TAG_OFF + (unsigned int)t;
        unsigned long long a0, a1, b0, b1;

#define LDH(X) __hip_atomic_load(&hbp[X], __ATOMIC_RELAXED, __HIP_MEMORY_SCOPE_AGENT)
        // ping-pong poll: two independent register sets, ~RT/2 detect granularity
        a0 = LDH(i0); a1 = LDH(i1);
        int guard = 0;
        for (;;) {
            b0 = LDH(i0); b1 = LDH(i1);
            bool okA = ((unsigned int)(a0 >> 32) == tag) & ((unsigned int)(a1 >> 32) == tag);
            if (__all(okA)) break;
            if (++guard > (1 << 20)) break;
            a0 = LDH(i0); a1 = LDH(i1);
            bool okB = ((unsigned int)(b0 >> 32) == tag) & ((unsigned int)(b1 >> 32) == tag);
            if (__all(okB)) { a0 = b0; a1 = b1; break; }
            if (++guard > (1 << 20)) break;
        }
#undef LDH

        // stage this wave's quarter into LDS
        hlds[i0] = __uint_as_float((unsigned int)a0);
        hlds[i1] = __uint_as_float((unsigned int)a1);
        __syncthreads();   // B1: full h visible to all waves

        // load full h fragment for this lane
        float hv[8];
#pragma unroll
        for (int kb = 0; kb < 8; ++kb)
            hv[kb] = hlds[kb * 64 + lane];

        // matvec partials: 8 row-pairs per lane, packed fp32 FMA (64 v2f)
        v2f acc2[8];
#pragma unroll
        for (int r2 = 0; r2 < 8; ++r2) acc2[r2] = (v2f)(0.f);
#pragma unroll
        for (int kb = 0; kb < 8; ++kb) {
            float h0 = hv[kb];
            v2f h2; h2.x = h0; h2.y = h0;
#pragma unroll
            for (int r2 = 0; r2 < 8; ++r2)
                acc2[r2] += wreg2[r2][kb] * h2;
        }

        // publish partials: physical row index = ul*4 + q (q = this wave w)
#pragma unroll
        for (int r2 = 0; r2 < 8; ++r2) {
            pacc[((2 * r2 + 0) * 4 + w) * 68 + lane] = acc2[r2].x;
            pacc[((2 * r2 + 1) * 4 + w) * 68 + lane] = acc2[r2].y;
        }
        __syncthreads();   // B2

        // reduce row r_phys = ul*4 + q = tid>>2: 4 threads x 16 values
        const float4* pr = (const float4*)&pacc[(tid >> 2) * 68 + sub * 16];
        float4 sv = pr[0];
#pragma unroll
        for (int j2 = 1; j2 < 4; ++j2) {
            float4 q4 = pr[j2];
            sv.x += q4.x; sv.y += q4.y; sv.z += q4.z; sv.w += q4.w;
        }
        float v = (sv.x + sv.y) + (sv.z + sv.w);
        v += __shfl_xor(v, 1, 64);
        v += __shfl_xor(v, 2, 64);
        v += gxv;
        float act = (q_g == 2) ? tanh_fast(v) : sigmoid_fast(v);

        // gather i/f/g/o within the 16-lane group (lanes g0l+4q), update, publish
        const int g0l = lane & ~15;
        float si = __shfl(act, g0l + 0,  64);
        float sf = __shfl(act, g0l + 4,  64);
        float tg = __shfl(act, g0l + 8,  64);
        float so = __shfl(act, g0l + 12, 64);
        if ((lane & 15) == 0) {
            c_state = sf * c_state + si * tg;
            float h_new = so * tanh_fast(c_state);
            unsigned long long pkt = ((unsigned long long)(TAG_OFF + (unsigned int)(t + 1)) << 32)
                                   | (unsigned long long)__float_as_uint(h_new);
            __hip_atomic_store(&hb[((size_t)(d * 2 + pn) * 2 + s) * H_DIM + bb * UPB + ul_g],
                               pkt, __ATOMIC_RELAXED, __HIP_MEMORY_SCOPE_AGENT);
        }
        // pacc/hlds WAR across steps protected by B1/B2:
        // any wave passing poll(t+1) implies ALL this block's waves published
        // step t (each wave publishes 4 of the 16 units), which in program
        // order follows their hlds/pacc reads for step t.
    }
}

// ---------------- k4a: head stage 1 — 16 blocks, each 32 output columns ----------------
// Reads blA/blB coalesced (32 consecutive j per lane group), 8 u-ranges per
// block; writes one partial of sum_j tanh(g_j)*out_w[j] per block.
__global__ __launch_bounds__(256) void k_head1(const unsigned long long* __restrict__ hb,
                                               const float* __restrict__ bi_w,
                                               const float* __restrict__ bi_b,
                                               const float* __restrict__ blA,
                                               const float* __restrict__ blB,
                                               const float* __restrict__ bl_b,
                                               const float* __restrict__ out_w,
                                               float* __restrict__ partial) {
    __shared__ float enc[2][512];
    __shared__ float red[8][36];
    const int tid = threadIdx.x;
    const int jl = tid & 31;            // j within block
    const int ur = tid >> 5;            // u-range 0..7 (64 u each)
    const int j  = blockIdx.x * 32 + jl;
    const float bw0 = bi_w[0], bw1 = bi_w[1], bib = bi_b[0];
    for (int u = tid; u < 512; u += 256) {
        // final h (t=2048) lives in parity 0
        float hfA = __uint_as_float((unsigned int)hb[((0 * 2 + 0) * 2 + 0) * 512 + u]);
        float hbA = __uint_as_float((unsigned int)hb[((1 * 2 + 0) * 2 + 0) * 512 + u]);
        float hfB = __uint_as_float((unsigned int)hb[((0 * 2 + 0) * 2 + 1) * 512 + u]);
        float hbB = __uint_as_float((unsigned int)hb[((1 * 2 + 0) * 2 + 1) * 512 + u]);
        enc[0][u] = bw0 * hfA + bw1 * hbA + bib;
        enc[1][u] = bw0 * hfB + bw1 * hbB + bib;
    }
    __syncthreads();
    float acc = 0.f;
    const int u0 = ur * 64;
#pragma unroll 8
    for (int k = 0; k < 64; ++k) {
        int u = u0 + k;
        acc += enc[0][u] * blA[(size_t)u * 512 + j] + enc[1][u] * blB[(size_t)u * 512 + j];
    }
    red[ur][jl] = acc;
    __syncthreads();
    if (tid < 32) {
        float a = bl_b[j];
#pragma unroll
        for (int r = 0; r < 8; ++r) a += red[r][tid];
        float c = tanh_fast(a) * out_w[j];
#pragma unroll
        for (int m = 1; m < 32; m <<= 1) c += __shfl_xor(c, m, 64);
        if (tid == 0) partial[blockIdx.x] = c;
    }
}

// ---------------- k4b: head stage 2 — finalize ----------------
__global__ void k_head2(const float* __restrict__ partial,
                        const float* __restrict__ out_b,
                        float* __restrict__ out) {
    const int l = threadIdx.x;          // 64 threads
    float v = (l < 16) ? partial[l] : 0.f;
#pragma unroll
    for (int m = 1; m < 16; m <<= 1) v += __shfl_xor(v, m, 64);
    if (l == 0) out[0] = sigmoid_fast(v + out_b[0]);
}

extern "C" void kernel_launch(void* const* d_in, const int* in_sizes, int n_in,
                              void* d_out, int out_size, void* d_ws, size_t ws_size,
                              hipStream_t stream) {
    const int*   sentA = (const int*)d_in[0];
    const int*   sentB = (const int*)d_in[1];
    // d_in[2] = hidden (unused by forward)
    const float* emb   = (const float*)d_in[3];
    const float* w_ih  = (const float*)d_in[4];
    const float* w_hh  = (const float*)d_in[5];
    const float* b_ih  = (const float*)d_in[6];
    const float* b_hh  = (const float*)d_in[7];
    const float* bi_w  = (const float*)d_in[8];
    const float* bi_b  = (const float*)d_in[9];
    const float* blA   = (const float*)d_in[10];
    const float* blB   = (const float*)d_in[11];
    const float* bl_b  = (const float*)d_in[12];
    const float* out_w = (const float*)d_in[13];
    const float* out_b = (const float*)d_in[14];
    float* out = (float*)d_out;

    char* ws = (char*)d_ws;
    unsigned long long* hbf = (unsigned long long*)(ws + WS_H);
    float*              x   = (float*)(ws + WS_X);
    __hip_bfloat16*     gx  = (__hip_bfloat16*)(ws + WS_GX);
    float*              par = (float*)(ws + WS_OUT);

    k_gather<<<dim3(128, 2), 256, 0, stream>>>(sentA, sentB, emb, x);
    k_gemm<<<dim3(32, 64, 4), 256, 0, stream>>>(x, w_ih, b_ih, b_hh, gx);
    k_rnn<<<dim3(128), 256, 0, stream>>>(w_hh, gx, hbf);
    k_head1<<<dim3(16), 256, 0, stream>>>(hbf, bi_w, bi_b, blA, blB, bl_b, out_w, par);
    k_head2<<<dim3(1), 64, 0, stream>>>(par, out_b, out);
}

// Round 9
// 4159.683 us; speedup vs baseline: 19.1143x; 1.0209x over previous
//
#include <hip/hip_runtime.h>
#include <hip/hip_bf16.h>

// Problem constants
#define T_LEN 2048
#define E_DIM 300
#define H_DIM 512
#define G_DIM 2048   // 4*H
#define NBLK  32     // blocks per (direction,sentence) chain in recurrent kernel
#define UPB   16     // hidden units per block (H/NBLK)
#define TAG_OFF 0x40000000u

// Workspace layout (bytes).
// xbf: [2 sent][2048][320] bf16 = 2,621,440   (cols 300..319 zero-padded)
// wbf: [2 dir ][2048][320] bf16 = 2,621,440
// hb : (value,tag) pairs [2 dir][2 parity][2 sent][512] u64 = 32 KB,
//      ALIASES xbf[0..32KB): xbf is fully consumed by k_gemm before
//      k_rnn's first hb store (same stream, sequential). A stale-bf16 tag
//      match would need bf16==2.0 exactly from ~N(0,0.1^2) data (~20 sigma).
// gx : [d*2+s][2048 t][32 bb][4 q][16 ul] bf16 = 33,554,432
#define WS_XBF  0
#define WS_WBF  2621440
#define WS_H    0
#define WS_GX   5242880
#define WS_OUT  38797312   // head partials: 16 f32

typedef float v2f __attribute__((ext_vector_type(2)));
typedef __attribute__((ext_vector_type(8))) short bf16x8;
typedef __attribute__((ext_vector_type(4))) float f32x4;

__device__ __forceinline__ float sigmoid_fast(float x) {
    return 1.f / (1.f + __expf(-x));
}
__device__ __forceinline__ float tanh_fast(float x) {
    x = fminf(fmaxf(x, -15.f), 15.f);
    float e = __expf(-2.f * x);
    return (1.f - e) / (1.f + e);
}
__device__ __forceinline__ unsigned short bf16b(float f) {
    __hip_bfloat16 h = __float2bfloat16(f);   // RNE
    unsigned short u; __builtin_memcpy(&u, &h, 2); return u;
}

// ---------------- k1: embedding gather -> bf16, zero-padded to 320 ----------------
__global__ void k_gather(const int* __restrict__ sentA, const int* __restrict__ sentB,
                         const float* __restrict__ emb, unsigned short* __restrict__ xbf) {
    const int s = blockIdx.y;
    const int* sent = s ? sentB : sentA;
    const int t0 = blockIdx.x * 16;
    for (int idx = threadIdx.x; idx < 16 * 80; idx += 256) {
        int r = idx / 80, c4 = idx - r * 80;
        int t = t0 + r;
        int row = sent[t];
        ushort4 o = {0, 0, 0, 0};
        if (c4 < 75) {
            float4 v = *(const float4*)(emb + (size_t)row * 300 + c4 * 4);
            o.x = bf16b(v.x); o.y = bf16b(v.y); o.z = bf16b(v.z); o.w = bf16b(v.w);
        }
        *(ushort4*)&xbf[((size_t)(s * 2048 + t)) * 320 + c4 * 4] = o;
    }
}

// ---------------- k1b: w_ih -> bf16 once (kills 64x redundant in-gemm conversion) ----------------
__global__ void k_conv_w(const float* __restrict__ w_ih, unsigned short* __restrict__ wbf) {
    const int r0 = blockIdx.x * 32;     // rows over [2 dir][2048 g]
    for (int idx = threadIdx.x; idx < 32 * 80; idx += 256) {
        int r = idx / 80, c4 = idx - r * 80;
        int row = r0 + r;
        ushort4 o = {0, 0, 0, 0};
        if (c4 < 75) {
            float4 v = *(const float4*)(w_ih + (size_t)row * 300 + c4 * 4);
            o.x = bf16b(v.x); o.y = bf16b(v.y); o.z = bf16b(v.z); o.w = bf16b(v.w);
        }
        *(ushort4*)&wbf[(size_t)row * 320 + c4 * 4] = o;
    }
}

// ---------------- k2: gx = x @ w_ih^T + (b_ih + b_hh), bf16 MFMA ----------------
// grid (32 gi, 64 ti, 4 = d*2+s), block 256 (4 waves). Block tile 32t x 64g,
// K padded to 320, 10 chunks of 32. Staging = pure unconditional 16B copies
// of pre-converted bf16 (no VALU conversion, half the global bytes of R8).
// Fragment pattern (guide m89/m92-verified): A = x rows [M][K], B = w rows
// [N][K] (B^T layout); both read as 8-bf16 runs at [lane&15][(lane>>4)*8];
// C/D: col(g)=lane&15, row(t)=(lane>>4)*4+reg.
#define KP 328   // padded LDS row stride in ushort (656B; 2-way banks on frag reads)
__global__ __launch_bounds__(256) void k_gemm(const unsigned short* __restrict__ xbf,
                                              const unsigned short* __restrict__ wbf,
                                              const float* __restrict__ b_ih,
                                              const float* __restrict__ b_hh,
                                              __hip_bfloat16* __restrict__ gx) {
    __shared__ unsigned short xs[32 * KP];
    __shared__ unsigned short ws_[64 * KP];
    const int gi = blockIdx.x, ti = blockIdx.y, z = blockIdx.z;
    const int d = z >> 1, s = z & 1;
    const int t0 = ti * 32, g0 = gi * 64;
    const int tid  = threadIdx.x;
    const int lane = tid & 63, w = tid >> 6;

    // stage x tile: 32 rows x 40 ushort8 units
    {
        const unsigned short* xr = xbf + ((size_t)(s * 2048 + t0)) * 320;
        for (int idx = tid; idx < 32 * 40; idx += 256) {
            int r = idx / 40, c8 = idx - r * 40;
            *(float4*)&xs[r * KP + c8 * 8] = *(const float4*)&xr[(size_t)r * 320 + c8 * 8];
        }
    }
    // stage w tile: 64 rows x 40 ushort8 units
    {
        const unsigned short* wr = wbf + ((size_t)(d * 2048 + g0)) * 320;
        for (int idx = tid; idx < 64 * 40; idx += 256) {
            int r = idx / 40, c8 = idx - r * 40;
            *(float4*)&ws_[r * KP + c8 * 8] = *(const float4*)&wr[(size_t)r * 320 + c8 * 8];
        }
    }
    __syncthreads();

    // wave w: m-strip mw = (w&1)*16, n-base nb = (w>>1)*32 (two 16-wide n-tiles)
    const int mw = (w & 1) * 16, nb = (w >> 1) * 32;
    const int fm = lane & 15;           // fragment m/n index
    const int fk = (lane >> 4) * 8;     // k offset within chunk
    f32x4 acc0 = {0.f, 0.f, 0.f, 0.f};
    f32x4 acc1 = {0.f, 0.f, 0.f, 0.f};
#pragma unroll
    for (int e0 = 0; e0 < 320; e0 += 32) {
        bf16x8 av  = *(const bf16x8*)&xs[(mw + fm) * KP + e0 + fk];
        bf16x8 bv0 = *(const bf16x8*)&ws_[(nb + fm) * KP + e0 + fk];
        bf16x8 bv1 = *(const bf16x8*)&ws_[(nb + 16 + fm) * KP + e0 + fk];
        acc0 = __builtin_amdgcn_mfma_f32_16x16x32_bf16(av, bv0, acc0, 0, 0, 0);
        acc1 = __builtin_amdgcn_mfma_f32_16x16x32_bf16(av, bv1, acc1, 0, 0, 0);
    }

    // epilogue: bias + bf16 store into block-sliced layout
    const int trowb = (lane >> 4) * 4;
#pragma unroll
    for (int nt = 0; nt < 2; ++nt) {
        f32x4 a = nt ? acc1 : acc0;
        int g = g0 + nb + nt * 16 + fm;
        float bias = b_ih[d * G_DIM + g] + b_hh[d * G_DIM + g];
        int pos = ((g >> 4) & 31) * 64 + (g >> 9) * 16 + (g & 15);
#pragma unroll
        for (int i = 0; i < 4; ++i) {
            int t = t0 + mw + trowb + i;
            int tout = d ? (T_LEN - 1 - t) : t;   // backward run: time-reversed rows
            gx[(((size_t)z * T_LEN + tout) << 11) + pos] = __float2bfloat16(a[i] + bias);
        }
    }
}

// ---------------- k3: recurrent LSTM, 128 blocks = (2 dir x 2 sent x 32) ----------------
// BYTE-IDENTICAL to the R1/R7/R8-verified kernel (3925-3938us, 3x reproduced).
// [R2-R6 post-mortems: block-merge, bf16-packing, 32x replication,
//  barrier-free wave-autonomy, and sc0 L2-handoff ALL regressed. This
//  geometry (64 lines/chain, quarter-split poll, 2-deep ping-pong,
//  16 contiguous publish stores) is the measured optimum; the round is
//  bounded by one agent-scope MALL round-trip (~1.5us), invariant to
//  exchange volume/fan-out/packing/barrier count.]
__global__ __launch_bounds__(256, 1) void k_rnn(const float* __restrict__ w_hh,
                                                const __hip_bfloat16* __restrict__ gx,
                                                unsigned long long* __restrict__ hb) {
    const int tid  = threadIdx.x;
    const int lane = tid & 63;
    const int w    = tid >> 6;          // wave index == gate row-block for matvec
    // reduce/gate-phase identity: tid = ul*16 + q*4 + sub
    const int sub  = tid & 3;
    const int q_g  = (tid >> 2) & 3;
    const int ul_g = tid >> 4;
    const int bid = blockIdx.x;         // (d*2+s)*32 + bb
    const int d  = bid >> 6;
    const int s  = (bid >> 5) & 1;
    const int bb = bid & 31;

    // persistent weights, row-paired: wreg2[r2][kb] = { W[w*512+bb*16+2r2][k], W[+1][k] }
    v2f wreg2[8][8];
#pragma unroll
    for (int r2 = 0; r2 < 8; ++r2)
#pragma unroll
        for (int kb = 0; kb < 8; ++kb) {
            const float* wp = w_hh + ((size_t)d * G_DIM + w * 512 + bb * 16 + 2 * r2) * H_DIM
                            + kb * 64 + lane;
            v2f t2; t2.x = wp[0]; t2.y = wp[H_DIM];
            wreg2[r2][kb] = t2;
        }

    __shared__ float hlds[H_DIM];       // staged h for this chain (2 KB)
    __shared__ float pacc[64 * 68];     // 64 rows (ul*4+q) x 64 lanes (+4 pad) ~17 KB

    float c_state = 0.f;

    // h_0 = 0, tag TAG_OFF, parity 0 (published by the 16 state-carrier threads)
    if ((lane & 15) == 0) {
        __hip_atomic_store(&hb[((size_t)(d * 2 + 0) * 2 + s) * H_DIM + bb * UPB + ul_g],
                           (unsigned long long)TAG_OFF << 32,
                           __ATOMIC_RELAXED, __HIP_MEMORY_SCOPE_AGENT);
    }

    // poll indices: wave w owns k-quarter [w*128, w*128+128) of its sentence
    const int i0 = w * 128 + lane;
    const int i1 = i0 + 64;

    for (int t = 0; t < T_LEN; ++t) {
        const int p  = t & 1;
        const int pn = p ^ 1;

        // prefetch this thread's gate input (overlaps the poll)
        float gxv = (float)gx[(((size_t)(d * 2 + s) * T_LEN + t) << 11)
                              + bb * 64 + q_g * 16 + ul_g];

        unsigned long long* hbp = hb + ((size_t)(d * 2 + p) * 2 + s) * H_DIM;
        const unsigned int tag = TAG_OFF + (unsigned int)t;
        unsigned long long a0, a1, b0, b1;

#define LDH(X) __hip_atomic_load(&hbp[X], __ATOMIC_RELAXED, __HIP_MEMORY_SCOPE_AGENT)
        // ping-pong poll: two independent register sets, ~RT/2 detect granularity
        a0 = LDH(i0); a1 = LDH(i1);
        int guard = 0;
        for (;;) {
            b0 = LDH(i0); b1 = LDH(i1);
            bool okA = ((unsigned int)(a0 >> 32) == tag) & ((unsigned int)(a1 >> 32) == tag);
            if (__all(okA)) break;
            if (++guard > (1 << 20)) break;
            a0 = LDH(i0); a1 = LDH(i1);
            bool okB = ((unsigned int)(b0 >> 32) == tag) & ((unsigned int)(b1 >> 32) == tag);
            if (__all(okB)) { a0 = b0; a1 = b1; break; }
            if (++guard > (1 << 20)) break;
        }
#undef LDH

        // stage this wave's quarter into LDS
        hlds[i0] = __uint_as_float((unsigned int)a0);
        hlds[i1] = __uint_as_float((unsigned int)a1);
        __syncthreads();   // B1: full h visible to all waves

        // load full h fragment for this lane
        float hv[8];
#pragma unroll
        for (int kb = 0; kb < 8; ++kb)
            hv[kb] = hlds[kb * 64 + lane];

        // matvec partials: 8 row-pairs per lane, packed fp32 FMA (64 v2f)
        v2f acc2[8];
#pragma unroll
        for (int r2 = 0; r2 < 8; ++r2) acc2[r2] = (v2f)(0.f);
#pragma unroll
        for (int kb = 0; kb < 8; ++kb) {
            float h0 = hv[kb];
            v2f h2; h2.x = h0; h2.y = h0;
#pragma unroll
            for (int r2 = 0; r2 < 8; ++r2)
                acc2[r2] += wreg2[r2][kb] * h2;
        }

        // publish partials: physical row index = ul*4 + q (q = this wave w)
#pragma unroll
        for (int r2 = 0; r2 < 8; ++r2) {
            pacc[((2 * r2 + 0) * 4 + w) * 68 + lane] = acc2[r2].x;
            pacc[((2 * r2 + 1) * 4 + w) * 68 + lane] = acc2[r2].y;
        }
        __syncthreads();   // B2

        // reduce row r_phys = ul*4 + q = tid>>2: 4 threads x 16 values
        const float4* pr = (const float4*)&pacc[(tid >> 2) * 68 + sub * 16];
        float4 sv = pr[0];
#pragma unroll
        for (int j2 = 1; j2 < 4; ++j2) {
            float4 q4 = pr[j2];
            sv.x += q4.x; sv.y += q4.y; sv.z += q4.z; sv.w += q4.w;
        }
        float v = (sv.x + sv.y) + (sv.z + sv.w);
        v += __shfl_xor(v, 1, 64);
        v += __shfl_xor(v, 2, 64);
        v += gxv;
        float act = (q_g == 2) ? tanh_fast(v) : sigmoid_fast(v);

        // gather i/f/g/o within the 16-lane group (lanes g0l+4q), update, publish
        const int g0l = lane & ~15;
        float si = __shfl(act, g0l + 0,  64);
        float sf = __shfl(act, g0l + 4,  64);
        float tg = __shfl(act, g0l + 8,  64);
        float so = __shfl(act, g0l + 12, 64);
        if ((lane & 15) == 0) {
            c_state = sf * c_state + si * tg;
            float h_new = so * tanh_fast(c_state);
            unsigned long long pkt = ((unsigned long long)(TAG_OFF + (unsigned int)(t + 1)) << 32)
                                   | (unsigned long long)__float_as_uint(h_new);
            __hip_atomic_store(&hb[((size_t)(d * 2 + pn) * 2 + s) * H_DIM + bb * UPB + ul_g],
                               pkt, __ATOMIC_RELAXED, __HIP_MEMORY_SCOPE_AGENT);
        }
        // pacc/hlds WAR across steps protected by B1/B2:
        // any wave passing poll(t+1) implies ALL this block's waves published
        // step t (each wave publishes 4 of the 16 units), which in program
        // order follows their hlds/pacc reads for step t.
    }
}

// ---------------- k4a: head stage 1 — 16 blocks, each 32 output columns ----------------
__global__ __launch_bounds__(256) void k_head1(const unsigned long long* __restrict__ hb,
                                               const float* __restrict__ bi_w,
                                               const float* __restrict__ bi_b,
                                               const float* __restrict__ blA,
                                               const float* __restrict__ blB,
                                               const float* __restrict__ bl_b,
                                               const float* __restrict__ out_w,
                                               float* __restrict__ partial) {
    __shared__ float enc[2][512];
    __shared__ float red[8][36];
    const int tid = threadIdx.x;
    const int jl = tid & 31;            // j within block
    const int ur = tid >> 5;            // u-range 0..7 (64 u each)
    const int j  = blockIdx.x * 32 + jl;
    const float bw0 = bi_w[0], bw1 = bi_w[1], bib = bi_b[0];
    for (int u = tid; u < 512; u += 256) {
        // final h (t=2048) lives in parity 0
        float hfA = __uint_as_float((unsigned int)hb[((0 * 2 + 0) * 2 + 0) * 512 + u]);
        float hbA = __uint_as_float((unsigned int)hb[((1 * 2 + 0) * 2 + 0) * 512 + u]);
        float hfB = __uint_as_float((unsigned int)hb[((0 * 2 + 0) * 2 + 1) * 512 + u]);
        float hbB = __uint_as_float((unsigned int)hb[((1 * 2 + 0) * 2 + 1) * 512 + u]);
        enc[0][u] = bw0 * hfA + bw1 * hbA + bib;
        enc[1][u] = bw0 * hfB + bw1 * hbB + bib;
    }
    __syncthreads();
    float acc = 0.f;
    const int u0 = ur * 64;
#pragma unroll 8
    for (int k = 0; k < 64; ++k) {
        int u = u0 + k;
        acc += enc[0][u] * blA[(size_t)u * 512 + j] + enc[1][u] * blB[(size_t)u * 512 + j];
    }
    red[ur][jl] = acc;
    __syncthreads();
    if (tid < 32) {
        float a = bl_b[j];
#pragma unroll
        for (int r = 0; r < 8; ++r) a += red[r][tid];
        float c = tanh_fast(a) * out_w[j];
#pragma unroll
        for (int m = 1; m < 32; m <<= 1) c += __shfl_xor(c, m, 64);
        if (tid == 0) partial[blockIdx.x] = c;
    }
}

// ---------------- k4b: head stage 2 — finalize ----------------
__global__ void k_head2(const float* __restrict__ partial,
                        const float* __restrict__ out_b,
                        float* __restrict__ out) {
    const int l = threadIdx.x;          // 64 threads
    float v = (l < 16) ? partial[l] : 0.f;
#pragma unroll
    for (int m = 1; m < 16; m <<= 1) v += __shfl_xor(v, m, 64);
    if (l == 0) out[0] = sigmoid_fast(v + out_b[0]);
}

extern "C" void kernel_launch(void* const* d_in, const int* in_sizes, int n_in,
                              void* d_out, int out_size, void* d_ws, size_t ws_size,
                              hipStream_t stream) {
    const int*   sentA = (const int*)d_in[0];
    const int*   sentB = (const int*)d_in[1];
    // d_in[2] = hidden (unused by forward)
    const float* emb   = (const float*)d_in[3];
    const float* w_ih  = (const float*)d_in[4];
    const float* w_hh  = (const float*)d_in[5];
    const float* b_ih  = (const float*)d_in[6];
    const float* b_hh  = (const float*)d_in[7];
    const float* bi_w  = (const float*)d_in[8];
    const float* bi_b  = (const float*)d_in[9];
    const float* blA   = (const float*)d_in[10];
    const float* blB   = (const float*)d_in[11];
    const float* bl_b  = (const float*)d_in[12];
    const float* out_w = (const float*)d_in[13];
    const float* out_b = (const float*)d_in[14];
    float* out = (float*)d_out;

    char* ws = (char*)d_ws;
    unsigned short*     xbf = (unsigned short*)(ws + WS_XBF);
    unsigned short*     wbf = (unsigned short*)(ws + WS_WBF);
    unsigned long long* hbf = (unsigned long long*)(ws + WS_H);
    __hip_bfloat16*     gx  = (__hip_bfloat16*)(ws + WS_GX);
    float*              par = (float*)(ws + WS_OUT);

    k_gather<<<dim3(128, 2), 256, 0, stream>>>(sentA, sentB, emb, xbf);
    k_conv_w<<<dim3(128), 256, 0, stream>>>(w_ih, wbf);
    k_gemm<<<dim3(32, 64, 4), 256, 0, stream>>>(xbf, wbf, b_ih, b_hh, gx);
    k_rnn<<<dim3(128), 256, 0, stream>>>(w_hh, gx, hbf);
    k_head1<<<dim3(16), 256, 0, stream>>>(hbf, bi_w, bi_b, blA, blB, bl_b, out_w, par);
    k_head2<<<dim3(1), 64, 0, stream>>>(par, out_b, out);
}